// Round 1
// baseline (3216.403 us; speedup 1.0000x reference)
//
#include <hip/hip_runtime.h>
#include <math.h>

#define S_LEN 2048
#define B_SZ 8
#define D_IN 1024
#define DS_ 128
#define INV_TEMP (1.0f/1.000001f)

// ---------------------------------------------------------------------------
// Kernel 1: fused projection GEMM  P[16384][512] = x[16384][1024] @ Wcat[512][1024]^T
// cols 0-127: W_k, 128-255: W_v, 256-383: W_q, 384-511: W_alpha_w
// BM=64, BN=64, BK=32, 256 threads, 4x4 per thread
// ---------------------------------------------------------------------------
__global__ __launch_bounds__(256) void proj_gemm(
    const float* __restrict__ X,
    const float* __restrict__ Wk, const float* __restrict__ Wv,
    const float* __restrict__ Wq, const float* __restrict__ Wa,
    float* __restrict__ P)
{
    __shared__ __align__(16) float As[32][68];
    __shared__ __align__(16) float Bs[32][68];
    const int tid = threadIdx.x;
    const int m0 = blockIdx.x * 64;
    const int n0 = blockIdx.y * 64;
    const int lr = tid >> 3;      // 0..31 row group
    const int lk4 = tid & 7;      // k-float4 index

    // resolve B row pointers once (n invariant over k-tiles)
    const float* wrows[2];
#pragma unroll
    for (int i = 0; i < 2; i++) {
        int nn = n0 + lr + i * 32;
        const float* w;
        if      (nn < 128) w = Wk + (size_t)nn * D_IN;
        else if (nn < 256) w = Wv + (size_t)(nn - 128) * D_IN;
        else if (nn < 384) w = Wq + (size_t)(nn - 256) * D_IN;
        else               w = Wa + (size_t)(nn - 384) * D_IN;
        wrows[i] = w;
    }
    const int ty = tid >> 4, tx = tid & 15;
    float acc[4][4];
#pragma unroll
    for (int i = 0; i < 4; i++)
#pragma unroll
        for (int j = 0; j < 4; j++) acc[i][j] = 0.f;

    for (int k0 = 0; k0 < D_IN; k0 += 32) {
#pragma unroll
        for (int i = 0; i < 2; i++) {
            int m = lr + i * 32;
            float4 a4 = *(const float4*)(X + (size_t)(m0 + m) * D_IN + k0 + lk4 * 4);
            As[lk4*4+0][m] = a4.x; As[lk4*4+1][m] = a4.y;
            As[lk4*4+2][m] = a4.z; As[lk4*4+3][m] = a4.w;
            float4 b4 = *(const float4*)(wrows[i] + k0 + lk4 * 4);
            Bs[lk4*4+0][m] = b4.x; Bs[lk4*4+1][m] = b4.y;
            Bs[lk4*4+2][m] = b4.z; Bs[lk4*4+3][m] = b4.w;
        }
        __syncthreads();
#pragma unroll
        for (int kk = 0; kk < 32; kk++) {
            float4 a4 = *(const float4*)(&As[kk][ty * 4]);
            float4 b4 = *(const float4*)(&Bs[kk][tx * 4]);
            float a[4] = {a4.x, a4.y, a4.z, a4.w};
            float b[4] = {b4.x, b4.y, b4.z, b4.w};
#pragma unroll
            for (int i = 0; i < 4; i++)
#pragma unroll
                for (int j = 0; j < 4; j++)
                    acc[i][j] = fmaf(a[i], b[j], acc[i][j]);
        }
        __syncthreads();
    }
#pragma unroll
    for (int i = 0; i < 4; i++) {
        float4 o; o.x = acc[i][0]; o.y = acc[i][1]; o.z = acc[i][2]; o.w = acc[i][3];
        *(float4*)(P + (size_t)(m0 + ty * 4 + i) * 512 + n0 + tx * 4) = o;
    }
}

// ---------------------------------------------------------------------------
// Kernel 2: in-place postprocess per token: l2norm(k), l2norm(q), alpha from r
// ---------------------------------------------------------------------------
__global__ __launch_bounds__(128) void postproc(
    float* __restrict__ P, const float* __restrict__ bA, const float* __restrict__ lam)
{
    const int tok = blockIdx.x, i = threadIdx.x;
    float* row = P + (size_t)tok * 512;
    float kr = row[i], qr = row[256 + i], rr = row[384 + i];
    float ks = kr * kr, qs = qr * qr;
#pragma unroll
    for (int m = 1; m < 64; m <<= 1) { ks += __shfl_xor(ks, m); qs += __shfl_xor(qs, m); }
    __shared__ float sb[4];
    if ((i & 63) == 0) { sb[(i >> 6) * 2] = ks; sb[(i >> 6) * 2 + 1] = qs; }
    __syncthreads();
    float kn = sqrtf(sb[0] + sb[2]);
    float qn = sqrtf(sb[1] + sb[3]);
    float kinv = 1.0f / fmaxf(kn, 1e-12f);
    float qinv = 1.0f / fmaxf(qn, 1e-12f);
    float sr = 1.0f / (1.0f + __expf(-(rr + bA[i])));
    float sl = 1.0f / (1.0f + __expf(-lam[i]));
    float la = logf(sl + 1e-8f);
    row[i]       = kr * kinv;
    row[256 + i] = qr * qinv;
    row[384 + i] = __expf(8.0f * sr * la);
}

// ---------------------------------------------------------------------------
// Kernel 3: the sequential recurrence. 8 blocks (1/batch) x 256 threads.
// Thread owns H[k][v] for k in [c*32,c*32+32), v in {2*vp, 2*vp+1}; H in regs.
// Per step: 3 dots (pred=q_t.H, kproj=k_t.H, y_{t-1}=q_{t-1}.H) over H_{t-1},
// err reduce -> sur -> elementwise H update. One barrier/step (triple-buffered
// staging, parity-buffered err partials).
// ---------------------------------------------------------------------------
__global__ __launch_bounds__(256) void recurrence(
    const float* __restrict__ P, float* __restrict__ Y)
{
    const int b = blockIdx.x;
    const int tid = threadIdx.x;
    const int c = tid & 3;
    const int vp = tid >> 2;       // 0..63
    const int lane = tid & 63;
    const int wave = tid >> 6;

    // padded staged layout: 4 sections (k,v,q,a) stride 144 floats, c-chunk stride 36
    __shared__ __align__(16) float Pbuf[3][576];
    __shared__ float errw[2][4];

    const float* Pb = P + (size_t)b * S_LEN * 512;
    float* Yb = Y + (size_t)b * S_LEN * DS_;

    float H0[32], H1[32];
#pragma unroll
    for (int j = 0; j < 32; j++) { H0[j] = 0.f; H1[j] = 0.f; }

    // zero LDS (q_{-1} garbage protection), then stage step 0
    for (int i = tid; i < 3 * 576; i += 256) (&Pbuf[0][0])[i] = 0.f;
    __syncthreads();
    {
        float2 v2 = *(const float2*)(Pb + tid * 2);
        int i0 = tid * 2, i1 = i0 + 1;
        Pbuf[0][(i0 >> 7) * 144 + ((i0 >> 5) & 3) * 36 + (i0 & 31)] = v2.x;
        Pbuf[0][(i1 >> 7) * 144 + ((i1 >> 5) & 3) * 36 + (i1 & 31)] = v2.y;
    }
    __syncthreads();

    const int voff = 144 + (vp >> 4) * 36 + ((2 * vp) & 31);

#define DOT_STEP(u, comp) { float h0 = H0[j4*4+u], h1 = H1[j4*4+u]; \
    pr0 = fmaf(q4.comp, h0, pr0); pr1 = fmaf(q4.comp, h1, pr1); \
    kp0 = fmaf(k4.comp, h0, kp0); kp1 = fmaf(k4.comp, h1, kp1); \
    yp0 = fmaf(p4.comp, h0, yp0); yp1 = fmaf(p4.comp, h1, yp1); }

#define UPD_STEP(u, comp) { float t0 = k4.comp * sd0, t1 = k4.comp * sd1; \
    H0[j4*4+u] = fmaf(a4.comp, H0[j4*4+u] - t0, t0); \
    H1[j4*4+u] = fmaf(a4.comp, H1[j4*4+u] - t1, t1); }

    for (int t = 0; t < S_LEN; t++) {
        const int pc = t % 3, pn = (t + 1) % 3, pp = (t + 2) % 3;
        const float* bq = &Pbuf[pc][2 * 144 + c * 36];
        const float* bk = &Pbuf[pc][c * 36];
        const float* bp = &Pbuf[pp][2 * 144 + c * 36];
        float pr0 = 0, pr1 = 0, kp0 = 0, kp1 = 0, yp0 = 0, yp1 = 0;
#pragma unroll
        for (int j4 = 0; j4 < 8; j4++) {
            float4 q4 = *(const float4*)(bq + j4 * 4);
            float4 k4 = *(const float4*)(bk + j4 * 4);
            float4 p4 = *(const float4*)(bp + j4 * 4);
            DOT_STEP(0, x) DOT_STEP(1, y) DOT_STEP(2, z) DOT_STEP(3, w)
        }
        // combine partial dots across the 4 k-quarters (lanes xor 1,2)
#pragma unroll
        for (int m = 1; m <= 2; m <<= 1) {
            pr0 += __shfl_xor(pr0, m); pr1 += __shfl_xor(pr1, m);
            kp0 += __shfl_xor(kp0, m); kp1 += __shfl_xor(kp1, m);
            yp0 += __shfl_xor(yp0, m); yp1 += __shfl_xor(yp1, m);
        }
        float2 vt = *(const float2*)(&Pbuf[pc][voff]);
        float e0 = vt.x - pr0, e1 = vt.y - pr1;
        float d0 = vt.x - kp0, d1 = vt.y - kp1;
        float ep = e0 * e0 + e1 * e1;
        ep += __shfl_xor(ep, 4); ep += __shfl_xor(ep, 8);
        ep += __shfl_xor(ep, 16); ep += __shfl_xor(ep, 32);
        if (lane == 0) errw[t & 1][wave] = ep * 0.25f;
        if (t > 0 && c == 0) {
            float2 yv; yv.x = yp0; yv.y = yp1;
            *(float2*)(Yb + (size_t)(t - 1) * DS_ + vp * 2) = yv;
        }
        if (t + 1 < S_LEN) {
            float2 v2 = *(const float2*)(Pb + (size_t)(t + 1) * 512 + tid * 2);
            int i0 = tid * 2, i1 = i0 + 1;
            Pbuf[pn][(i0 >> 7) * 144 + ((i0 >> 5) & 3) * 36 + (i0 & 31)] = v2.x;
            Pbuf[pn][(i1 >> 7) * 144 + ((i1 >> 5) & 3) * 36 + (i1 & 31)] = v2.y;
        }
        __syncthreads();
        float err = errw[t & 1][0] + errw[t & 1][1] + errw[t & 1][2] + errw[t & 1][3];
        float sur = 1.0f / (1.0f + __expf(-err * INV_TEMP));
        float sd0 = sur * d0, sd1 = sur * d1;
        const float* ba = &Pbuf[pc][3 * 144 + c * 36];
#pragma unroll
        for (int j4 = 0; j4 < 8; j4++) {
            float4 a4 = *(const float4*)(ba + j4 * 4);
            float4 k4 = *(const float4*)(bk + j4 * 4);
            UPD_STEP(0, x) UPD_STEP(1, y) UPD_STEP(2, z) UPD_STEP(3, w)
        }
    }
    // epilogue: y_{S-1} = q_{S-1}^T H_{S-1}
    {
        const float* bq = &Pbuf[(S_LEN - 1) % 3][2 * 144 + c * 36];
        float y0 = 0, y1 = 0;
#pragma unroll
        for (int j4 = 0; j4 < 8; j4++) {
            float4 q4 = *(const float4*)(bq + j4 * 4);
            y0 = fmaf(q4.x, H0[j4*4+0], y0); y1 = fmaf(q4.x, H1[j4*4+0], y1);
            y0 = fmaf(q4.y, H0[j4*4+1], y0); y1 = fmaf(q4.y, H1[j4*4+1], y1);
            y0 = fmaf(q4.z, H0[j4*4+2], y0); y1 = fmaf(q4.z, H1[j4*4+2], y1);
            y0 = fmaf(q4.w, H0[j4*4+3], y0); y1 = fmaf(q4.w, H1[j4*4+3], y1);
        }
        y0 += __shfl_xor(y0, 1); y0 += __shfl_xor(y0, 2);
        y1 += __shfl_xor(y1, 1); y1 += __shfl_xor(y1, 2);
        if (c == 0) {
            float2 yv; yv.x = y0; yv.y = y1;
            *(float2*)(Yb + (size_t)(S_LEN - 1) * DS_ + vp * 2) = yv;
        }
    }
#undef DOT_STEP
#undef UPD_STEP
}

// ---------------------------------------------------------------------------
// Kernel 4: RMSNorm over DS per token
// ---------------------------------------------------------------------------
__global__ __launch_bounds__(128) void rmsnorm(
    const float* __restrict__ Y, const float* __restrict__ nw, float* __restrict__ Yn)
{
    const int tok = blockIdx.x, i = threadIdx.x;
    float y = Y[(size_t)tok * DS_ + i];
    float s = y * y;
#pragma unroll
    for (int m = 1; m < 64; m <<= 1) s += __shfl_xor(s, m);
    __shared__ float sb[2];
    if ((i & 63) == 0) sb[i >> 6] = s;
    __syncthreads();
    float ms = (sb[0] + sb[1]) * (1.0f / 128.0f);
    Yn[(size_t)tok * DS_ + i] = y * rsqrtf(ms + 1e-6f) * nw[i];
}

// ---------------------------------------------------------------------------
// Kernel 5: output GEMM  Out[16384][1024] = Yn[16384][128] @ Wo[1024][128]^T
// ---------------------------------------------------------------------------
__global__ __launch_bounds__(256) void out_gemm(
    const float* __restrict__ Yn, const float* __restrict__ Wo, float* __restrict__ Out)
{
    __shared__ __align__(16) float As[32][68];
    __shared__ __align__(16) float Bs[32][68];
    const int tid = threadIdx.x;
    const int m0 = blockIdx.x * 64;
    const int n0 = blockIdx.y * 64;
    const int lr = tid >> 3;
    const int lk4 = tid & 7;
    const int ty = tid >> 4, tx = tid & 15;
    float acc[4][4];
#pragma unroll
    for (int i = 0; i < 4; i++)
#pragma unroll
        for (int j = 0; j < 4; j++) acc[i][j] = 0.f;

    for (int k0 = 0; k0 < DS_; k0 += 32) {
#pragma unroll
        for (int i = 0; i < 2; i++) {
            int m = lr + i * 32;
            float4 a4 = *(const float4*)(Yn + (size_t)(m0 + m) * DS_ + k0 + lk4 * 4);
            As[lk4*4+0][m] = a4.x; As[lk4*4+1][m] = a4.y;
            As[lk4*4+2][m] = a4.z; As[lk4*4+3][m] = a4.w;
            float4 b4 = *(const float4*)(Wo + (size_t)(n0 + m) * DS_ + k0 + lk4 * 4);
            Bs[lk4*4+0][m] = b4.x; Bs[lk4*4+1][m] = b4.y;
            Bs[lk4*4+2][m] = b4.z; Bs[lk4*4+3][m] = b4.w;
        }
        __syncthreads();
#pragma unroll
        for (int kk = 0; kk < 32; kk++) {
            float4 a4 = *(const float4*)(&As[kk][ty * 4]);
            float4 b4 = *(const float4*)(&Bs[kk][tx * 4]);
            float a[4] = {a4.x, a4.y, a4.z, a4.w};
            float b[4] = {b4.x, b4.y, b4.z, b4.w};
#pragma unroll
            for (int i = 0; i < 4; i++)
#pragma unroll
                for (int j = 0; j < 4; j++)
                    acc[i][j] = fmaf(a[i], b[j], acc[i][j]);
        }
        __syncthreads();
    }
#pragma unroll
    for (int i = 0; i < 4; i++) {
        float4 o; o.x = acc[i][0]; o.y = acc[i][1]; o.z = acc[i][2]; o.w = acc[i][3];
        *(float4*)(Out + (size_t)(m0 + ty * 4 + i) * 1024 + n0 + tx * 4) = o;
    }
}

// ---------------------------------------------------------------------------
extern "C" void kernel_launch(void* const* d_in, const int* in_sizes, int n_in,
                              void* d_out, int out_size, void* d_ws, size_t ws_size,
                              hipStream_t stream)
{
    const float* x   = (const float*)d_in[0];
    const float* Wk  = (const float*)d_in[1];
    const float* Wv  = (const float*)d_in[2];
    const float* Wq  = (const float*)d_in[3];
    const float* Waw = (const float*)d_in[4];
    const float* Wab = (const float*)d_in[5];
    const float* lam = (const float*)d_in[6];
    const float* Wo  = (const float*)d_in[7];
    const float* nw  = (const float*)d_in[8];
    float* out = (float*)d_out;

    const size_t NTOK = (size_t)B_SZ * S_LEN;   // 16384
    float* P  = (float*)d_ws;                    // NTOK*512
    float* Y  = P + NTOK * 512;                  // NTOK*128
    float* Yn = Y + NTOK * DS_;                  // NTOK*128

    proj_gemm<<<dim3(NTOK / 64, 512 / 64), 256, 0, stream>>>(x, Wk, Wv, Wq, Waw, P);
    postproc<<<NTOK, 128, 0, stream>>>(P, Wab, lam);
    recurrence<<<B_SZ, 256, 0, stream>>>(P, Y);
    rmsnorm<<<NTOK, 128, 0, stream>>>(Y, nw, Yn);
    out_gemm<<<dim3(NTOK / 64, 1024 / 64), 256, 0, stream>>>(Yn, Wo, out);
}

// Round 2
// 3003.094 us; speedup vs baseline: 1.0710x; 1.0710x over previous
//
#include <hip/hip_runtime.h>
#include <math.h>

#define S_LEN 2048
#define B_SZ 8
#define D_IN 1024
#define DS_ 128
#define INV_TEMP (1.0f/1.000001f)

// ---------------------------------------------------------------------------
// Kernel 1: fused projection GEMM  P[16384][512] = x[16384][1024] @ Wcat[512][1024]^T
// cols 0-127: W_k, 128-255: W_v, 256-383: W_q, 384-511: W_alpha_w
// ---------------------------------------------------------------------------
__global__ __launch_bounds__(256) void proj_gemm(
    const float* __restrict__ X,
    const float* __restrict__ Wk, const float* __restrict__ Wv,
    const float* __restrict__ Wq, const float* __restrict__ Wa,
    float* __restrict__ P)
{
    __shared__ __align__(16) float As[32][68];
    __shared__ __align__(16) float Bs[32][68];
    const int tid = threadIdx.x;
    const int m0 = blockIdx.x * 64;
    const int n0 = blockIdx.y * 64;
    const int lr = tid >> 3;
    const int lk4 = tid & 7;

    const float* wrows[2];
#pragma unroll
    for (int i = 0; i < 2; i++) {
        int nn = n0 + lr + i * 32;
        const float* w;
        if      (nn < 128) w = Wk + (size_t)nn * D_IN;
        else if (nn < 256) w = Wv + (size_t)(nn - 128) * D_IN;
        else if (nn < 384) w = Wq + (size_t)(nn - 256) * D_IN;
        else               w = Wa + (size_t)(nn - 384) * D_IN;
        wrows[i] = w;
    }
    const int ty = tid >> 4, tx = tid & 15;
    float acc[4][4];
#pragma unroll
    for (int i = 0; i < 4; i++)
#pragma unroll
        for (int j = 0; j < 4; j++) acc[i][j] = 0.f;

    for (int k0 = 0; k0 < D_IN; k0 += 32) {
#pragma unroll
        for (int i = 0; i < 2; i++) {
            int m = lr + i * 32;
            float4 a4 = *(const float4*)(X + (size_t)(m0 + m) * D_IN + k0 + lk4 * 4);
            As[lk4*4+0][m] = a4.x; As[lk4*4+1][m] = a4.y;
            As[lk4*4+2][m] = a4.z; As[lk4*4+3][m] = a4.w;
            float4 b4 = *(const float4*)(wrows[i] + k0 + lk4 * 4);
            Bs[lk4*4+0][m] = b4.x; Bs[lk4*4+1][m] = b4.y;
            Bs[lk4*4+2][m] = b4.z; Bs[lk4*4+3][m] = b4.w;
        }
        __syncthreads();
#pragma unroll
        for (int kk = 0; kk < 32; kk++) {
            float4 a4 = *(const float4*)(&As[kk][ty * 4]);
            float4 b4 = *(const float4*)(&Bs[kk][tx * 4]);
            float a[4] = {a4.x, a4.y, a4.z, a4.w};
            float b[4] = {b4.x, b4.y, b4.z, b4.w};
#pragma unroll
            for (int i = 0; i < 4; i++)
#pragma unroll
                for (int j = 0; j < 4; j++)
                    acc[i][j] = fmaf(a[i], b[j], acc[i][j]);
        }
        __syncthreads();
    }
#pragma unroll
    for (int i = 0; i < 4; i++) {
        float4 o; o.x = acc[i][0]; o.y = acc[i][1]; o.z = acc[i][2]; o.w = acc[i][3];
        *(float4*)(P + (size_t)(m0 + ty * 4 + i) * 512 + n0 + tx * 4) = o;
    }
}

// ---------------------------------------------------------------------------
// Kernel 2: postprocess per token: l2norm(k), l2norm(q), alpha from r,
// and g[tok] = sum_k q_k*(1-alpha_k)*k_k  (for the y_t algebra in recurrence)
// ---------------------------------------------------------------------------
__global__ __launch_bounds__(128) void postproc(
    float* __restrict__ P, float* __restrict__ G,
    const float* __restrict__ bA, const float* __restrict__ lam)
{
    const int tok = blockIdx.x, i = threadIdx.x;
    float* row = P + (size_t)tok * 512;
    float kr = row[i], qr = row[256 + i], rr = row[384 + i];
    float ks = kr * kr, qs = qr * qr;
#pragma unroll
    for (int m = 1; m < 64; m <<= 1) { ks += __shfl_xor(ks, m); qs += __shfl_xor(qs, m); }
    __shared__ float sb[6];
    if ((i & 63) == 0) { sb[(i >> 6) * 2] = ks; sb[(i >> 6) * 2 + 1] = qs; }
    __syncthreads();
    float kinv = 1.0f / fmaxf(sqrtf(sb[0] + sb[2]), 1e-12f);
    float qinv = 1.0f / fmaxf(sqrtf(sb[1] + sb[3]), 1e-12f);
    float kn = kr * kinv, qn = qr * qinv;
    float sr = 1.0f / (1.0f + __expf(-(rr + bA[i])));
    float sl = 1.0f / (1.0f + __expf(-lam[i]));
    float la = logf(sl + 1e-8f);
    float al = __expf(8.0f * sr * la);
    row[i]       = kn;
    row[256 + i] = qn;
    row[384 + i] = al;
    float gi = qn * (1.0f - al) * kn;
#pragma unroll
    for (int m = 1; m < 64; m <<= 1) gi += __shfl_xor(gi, m);
    if ((i & 63) == 0) sb[4 + (i >> 6)] = gi;
    __syncthreads();
    if (i == 0) G[tok] = sb[4] + sb[5];
}

// ---------------------------------------------------------------------------
// Kernel 3: sequential recurrence. 8 blocks x 512 threads (2 waves/SIMD).
// Thread (c=tid&7, vp=tid>>3) owns H[k][v] for k in [c*16,c*16+16), v in {2vp,2vp+1}.
// Per step: dots pred=q.H, kproj=k.H, ya=(q*a).H over H_{t-1} (k,a kept in regs
// for the update -> update phase has ZERO LDS reads). y_t = ya + sur*g*d.
// Global prefetch 2 steps deep (issue t+2 at step t, LDS-write t+1 at step t),
// one barrier per step, triple-buffered staging, parity-buffered err partials.
// LDS layout: sections k/v/q/a at 0/160/320/480, 8 chunks of 16 floats with
// stride 20 (pad 4) -> the 8 broadcast groups of a b128 read hit disjoint banks.
// ---------------------------------------------------------------------------
__global__ __launch_bounds__(512, 2) void recurrence(
    const float* __restrict__ P, const float* __restrict__ G, float* __restrict__ Y)
{
    const int b = blockIdx.x;
    const int tid = threadIdx.x;
    const int c = tid & 7;
    const int vp = tid >> 3;       // 0..63 (v pair)
    const int lane = tid & 63;
    const int wave = tid >> 6;     // 0..7

    __shared__ __align__(16) float Pbuf[3][808];
    __shared__ __align__(16) float errw[2][8];

    const float* Pb = P + (size_t)b * S_LEN * 512;
    const float* Gb = G + (size_t)b * S_LEN;
    float* Yb = Y + (size_t)b * S_LEN * DS_;

    float H0[16], H1[16];
#pragma unroll
    for (int j = 0; j < 16; j++) { H0[j] = 0.f; H1[j] = 0.f; }

    const bool isP = tid < 256;
    const bool isG = (tid == 256);
    int spos = 0;
    if (isP) {
        int i0 = tid * 2, sec = i0 >> 7, idx = i0 & 127;
        spos = sec * 160 + (idx >> 4) * 20 + (idx & 15);
    }
    const int voff = 160 + (vp >> 3) * 20 + ((2 * vp) & 15);

    float2 rp0, rp1; float rg0 = 0.f, rg1 = 0.f;
    if (isP) {
        rp0 = *(const float2*)(Pb + tid * 2);
        rp1 = *(const float2*)(Pb + 512 + tid * 2);
    }
    if (isG) { rg0 = Gb[0]; rg1 = Gb[1]; }
    if (isP) *(float2*)(&Pbuf[0][spos]) = rp0;
    if (isG) Pbuf[0][800] = rg0;
    __syncthreads();

#define DOTC(j, u, comp) { \
    float q_ = q4[j].comp, k_ = k4[j].comp, a_ = a4[j].comp; \
    float h0 = H0[(j)*4+(u)], h1 = H1[(j)*4+(u)]; \
    pr0 = fmaf(q_, h0, pr0); pr1 = fmaf(q_, h1, pr1); \
    kp0 = fmaf(k_, h0, kp0); kp1 = fmaf(k_, h1, kp1); \
    float qa_ = q_ * a_; \
    ya0 = fmaf(qa_, h0, ya0); ya1 = fmaf(qa_, h1, ya1); }

#define UPDC(j, u, comp) { \
    float k_ = k4[j].comp, a_ = a4[j].comp; \
    float t0 = k_ * sd0, t1 = k_ * sd1; \
    H0[(j)*4+(u)] = fmaf(a_, H0[(j)*4+(u)] - t0, t0); \
    H1[(j)*4+(u)] = fmaf(a_, H1[(j)*4+(u)] - t1, t1); }

#define STEP(T, PAR, RPS, RGS, RPL, RGL) { \
    float* cb = &Pbuf[(T) % 3][0]; \
    const float* bk = cb + c * 20; \
    float4 k4[4], q4[4], a4[4]; \
    _Pragma("unroll") for (int j = 0; j < 4; j++) { \
        k4[j] = *(const float4*)(bk + j * 4); \
        q4[j] = *(const float4*)(bk + 320 + j * 4); \
        a4[j] = *(const float4*)(bk + 480 + j * 4); } \
    float2 vt = *(const float2*)(cb + voff); \
    float g = cb[800]; \
    float pr0 = 0, pr1 = 0, kp0 = 0, kp1 = 0, ya0 = 0, ya1 = 0; \
    _Pragma("unroll") for (int j = 0; j < 4; j++) { \
        DOTC(j, 0, x) DOTC(j, 1, y) DOTC(j, 2, z) DOTC(j, 3, w) } \
    _Pragma("unroll") for (int m = 1; m <= 4; m <<= 1) { \
        pr0 += __shfl_xor(pr0, m); pr1 += __shfl_xor(pr1, m); \
        kp0 += __shfl_xor(kp0, m); kp1 += __shfl_xor(kp1, m); \
        ya0 += __shfl_xor(ya0, m); ya1 += __shfl_xor(ya1, m); } \
    float e0 = vt.x - pr0, e1 = vt.y - pr1; \
    float d0 = vt.x - kp0, d1 = vt.y - kp1; \
    float ep = fmaf(e0, e0, e1 * e1); \
    ep += __shfl_xor(ep, 8); ep += __shfl_xor(ep, 16); ep += __shfl_xor(ep, 32); \
    if (lane == 0) errw[PAR][wave] = ep; \
    if ((T) + 1 < S_LEN) { \
        if (isP) *(float2*)(&Pbuf[((T) + 1) % 3][spos]) = RPS; \
        if (isG) Pbuf[((T) + 1) % 3][800] = RGS; } \
    if ((T) + 2 < S_LEN) { \
        if (isP) RPL = *(const float2*)(Pb + (size_t)((T) + 2) * 512 + tid * 2); \
        if (isG) RGL = Gb[(T) + 2]; } \
    __syncthreads(); \
    float4 ea = *(const float4*)(&errw[PAR][0]); \
    float4 eb = *(const float4*)(&errw[PAR][4]); \
    float err = ((ea.x + ea.y) + (ea.z + ea.w)) + ((eb.x + eb.y) + (eb.z + eb.w)); \
    float sur = 1.0f / (1.0f + __expf(-err * INV_TEMP)); \
    float sd0 = sur * d0, sd1 = sur * d1; \
    if (c == 0) { \
        float2 yv; float sg = sur * g; \
        yv.x = fmaf(sg, d0, ya0); yv.y = fmaf(sg, d1, ya1); \
        *(float2*)(Yb + (size_t)(T) * DS_ + vp * 2) = yv; } \
    _Pragma("unroll") for (int j = 0; j < 4; j++) { \
        UPDC(j, 0, x) UPDC(j, 1, y) UPDC(j, 2, z) UPDC(j, 3, w) } \
}

    for (int t = 0; t < S_LEN; t += 2) {
        STEP(t,     0, rp1, rg1, rp0, rg0)
        STEP(t + 1, 1, rp0, rg0, rp1, rg1)
    }
#undef DOTC
#undef UPDC
#undef STEP
}

// ---------------------------------------------------------------------------
// Kernel 4: RMSNorm over DS per token
// ---------------------------------------------------------------------------
__global__ __launch_bounds__(128) void rmsnorm(
    const float* __restrict__ Y, const float* __restrict__ nw, float* __restrict__ Yn)
{
    const int tok = blockIdx.x, i = threadIdx.x;
    float y = Y[(size_t)tok * DS_ + i];
    float s = y * y;
#pragma unroll
    for (int m = 1; m < 64; m <<= 1) s += __shfl_xor(s, m);
    __shared__ float sb[2];
    if ((i & 63) == 0) sb[i >> 6] = s;
    __syncthreads();
    float ms = (sb[0] + sb[1]) * (1.0f / 128.0f);
    Yn[(size_t)tok * DS_ + i] = y * rsqrtf(ms + 1e-6f) * nw[i];
}

// ---------------------------------------------------------------------------
// Kernel 5: output GEMM  Out[16384][1024] = Yn[16384][128] @ Wo[1024][128]^T
// ---------------------------------------------------------------------------
__global__ __launch_bounds__(256) void out_gemm(
    const float* __restrict__ Yn, const float* __restrict__ Wo, float* __restrict__ Out)
{
    __shared__ __align__(16) float As[32][68];
    __shared__ __align__(16) float Bs[32][68];
    const int tid = threadIdx.x;
    const int m0 = blockIdx.x * 64;
    const int n0 = blockIdx.y * 64;
    const int lr = tid >> 3;
    const int lk4 = tid & 7;
    const int ty = tid >> 4, tx = tid & 15;
    float acc[4][4];
#pragma unroll
    for (int i = 0; i < 4; i++)
#pragma unroll
        for (int j = 0; j < 4; j++) acc[i][j] = 0.f;

    for (int k0 = 0; k0 < DS_; k0 += 32) {
#pragma unroll
        for (int i = 0; i < 2; i++) {
            int m = lr + i * 32;
            float4 a4 = *(const float4*)(Yn + (size_t)(m0 + m) * DS_ + k0 + lk4 * 4);
            As[lk4*4+0][m] = a4.x; As[lk4*4+1][m] = a4.y;
            As[lk4*4+2][m] = a4.z; As[lk4*4+3][m] = a4.w;
            float4 b4 = *(const float4*)(Wo + (size_t)(n0 + m) * DS_ + k0 + lk4 * 4);
            Bs[lk4*4+0][m] = b4.x; Bs[lk4*4+1][m] = b4.y;
            Bs[lk4*4+2][m] = b4.z; Bs[lk4*4+3][m] = b4.w;
        }
        __syncthreads();
#pragma unroll
        for (int kk = 0; kk < 32; kk++) {
            float4 a4 = *(const float4*)(&As[kk][ty * 4]);
            float4 b4 = *(const float4*)(&Bs[kk][tx * 4]);
            float a[4] = {a4.x, a4.y, a4.z, a4.w};
            float b[4] = {b4.x, b4.y, b4.z, b4.w};
#pragma unroll
            for (int i = 0; i < 4; i++)
#pragma unroll
                for (int j = 0; j < 4; j++)
                    acc[i][j] = fmaf(a[i], b[j], acc[i][j]);
        }
        __syncthreads();
    }
#pragma unroll
    for (int i = 0; i < 4; i++) {
        float4 o; o.x = acc[i][0]; o.y = acc[i][1]; o.z = acc[i][2]; o.w = acc[i][3];
        *(float4*)(Out + (size_t)(m0 + ty * 4 + i) * 1024 + n0 + tx * 4) = o;
    }
}

// ---------------------------------------------------------------------------
extern "C" void kernel_launch(void* const* d_in, const int* in_sizes, int n_in,
                              void* d_out, int out_size, void* d_ws, size_t ws_size,
                              hipStream_t stream)
{
    const float* x   = (const float*)d_in[0];
    const float* Wk  = (const float*)d_in[1];
    const float* Wv  = (const float*)d_in[2];
    const float* Wq  = (const float*)d_in[3];
    const float* Waw = (const float*)d_in[4];
    const float* Wab = (const float*)d_in[5];
    const float* lam = (const float*)d_in[6];
    const float* Wo  = (const float*)d_in[7];
    const float* nw  = (const float*)d_in[8];
    float* out = (float*)d_out;

    const size_t NTOK = (size_t)B_SZ * S_LEN;   // 16384
    float* P  = (float*)d_ws;                    // NTOK*512
    float* Y  = P + NTOK * 512;                  // NTOK*128
    float* Yn = Y + NTOK * DS_;                  // NTOK*128
    float* G  = Yn + NTOK * DS_;                 // NTOK

    proj_gemm<<<dim3(NTOK / 64, 512 / 64), 256, 0, stream>>>(x, Wk, Wv, Wq, Waw, P);
    postproc<<<NTOK, 128, 0, stream>>>(P, G, Wab, lam);
    recurrence<<<B_SZ, 512, 0, stream>>>(P, G, Y);
    rmsnorm<<<NTOK, 128, 0, stream>>>(Y, nw, Yn);
    out_gemm<<<dim3(NTOK / 64, 1024 / 64), 256, 0, stream>>>(Yn, Wo, out);
}